// Round 30
// baseline (33.273 us; speedup 1.0000x reference)
//
#include <hip/hip_runtime.h>

#define NB   4
#define CIN  32
#define HH   56
#define WW   56
#define GOUT 8
#define LOUT 8
#define KK   9
#define HW   (HH * WW)        // 3136
#define WSLICE 2304           // GOUT-slice floats per c (8*9*4*8)
#define WS_G 292              // padded per-g LDS stride -> conflict-free float4 reads
#define WS_C (8 * WS_G)       // 2336 floats per staged c-slice
#define CPB  2                // c's per block (amortize x-gather + staging)
#define HP   58               // padded spatial dims
#define WP   58
#define THREADS 448           // one image row: 56 px * 8 g

typedef float v2f __attribute__((ext_vector_type(2)));
typedef float v4f __attribute__((ext_vector_type(4)));

static __device__ __forceinline__ v2f fma2(v2f a, v2f b, v2f c) {
    return __builtin_elementwise_fma(a, b, c);
}

// DPP xor-add over the 8-lane g-group: quad_perm(1,0,3,2)=0xB1 (lane^1),
// quad_perm(2,3,0,1)=0x4E (lane^2), row_half_mirror=0x141 (lane^7 within 8;
// valid for step 3 because quad-sums are already quad-uniform).
#define DPP_XADD(x, CTRL) \
    (x) += __int_as_float(__builtin_amdgcn_update_dpp( \
        0, __float_as_int(x), (CTRL), 0xF, 0xF, true))

// ---- pre-pass: x[n][ch][h][w] -> xt[n][hp][wp][ch] with zero border ----
__global__ __launch_bounds__(256) void transpose_x_kernel(
    const float* __restrict__ x, float* __restrict__ xt)
{
    __shared__ float tile[CIN * 57];     // 57 stride: conflict-free transposed read
    const int b = blockIdx.x;            // n*HP + hp
    const int n = b / HP;
    const int hp = b - n * HP;
    const int h = hp - 1;
    const int tid = threadIdx.x;
    const bool rowok = (unsigned)h < (unsigned)HH;

    if (rowok) {
        for (int i = tid; i < CIN * WW; i += 256) {
            const int ch = i / WW;
            const int w  = i - ch * WW;  // lanes: w consecutive -> coalesced read
            tile[ch * 57 + w] = x[((n * CIN + ch) * HH + h) * WW + w];
        }
    }
    __syncthreads();
    float* dst = xt + ((size_t)(n * HP + hp) * WP) * CIN;
    for (int i = tid; i < WP * CIN; i += 256) {
        const int wp = i >> 5;
        const int ch = i & 31;           // lanes: ch consecutive -> coalesced write
        const bool ok = rowok && (wp >= 1) && (wp <= WW);
        dst[i] = ok ? tile[ch * 57 + (wp - 1)] : 0.0f;
    }
}

// 2 c's per block: x-gather, addressing, staging barrier amortized 2x.
// (448,2) keeps the 256-reg budget (r14's spill was at 128) — xv4 stays
// live across both c-iterations; pr2's live range recycles between them.
__global__ __launch_bounds__(THREADS, 2) void caps_routing_kernel(
    const float* __restrict__ xt, const float* __restrict__ wt,
    float* __restrict__ out)
{
    __shared__ __align__(16) float ws[CPB * WS_C];   // 18688 B

    const int tid = threadIdx.x;
    const int c0 = blockIdx.y * CPB;
    const int rr = blockIdx.x;        // n*56 + h  (block-uniform -> SALU math)
    const int n = rr / HH;
    const int h = rr - n * HH;

    const int g = tid & 7;
    const int w = tid >> 3;           // 0..55

    // ---- x-gather: 9 unconditional float4 loads (padded layout), once ----
    v4f xv4[KK];
    const float* base = xt + ((size_t)((n * HP + h) * WP + w)) * CIN + g * 4;
    #pragma unroll
    for (int ki = 0; ki < 3; ++ki)
        #pragma unroll
        for (int kj = 0; kj < 3; ++kj)
            xv4[ki * 3 + kj] =
                *reinterpret_cast<const v4f*>(base + (ki * WP + kj) * CIN);

    // ---- stage BOTH c-slices: [cc][g][k][l][m], per-g padded to 292 ----
    if (tid < 256) {
        const int gg = tid >> 5;
        const int r0 = tid & 31;
        #pragma unroll
        for (int cc = 0; cc < CPB; ++cc) {
            const float* src = wt + (c0 + cc) * WSLICE + gg * 288;
            float* dst = ws + cc * WS_C + gg * WS_G;
            #pragma unroll
            for (int j = 0; j < 9; ++j)
                dst[r0 + j * 32] = src[r0 + j * 32];
        }
    }
    __syncthreads();

    #pragma unroll
    for (int cc = 0; cc < CPB; ++cc) {
        // ---- priors (packed pairs): pr2[k][j] = m-pair j of prior vector k ----
        v2f pr2[KK][4];
        v2f ks2[4] = {v2f{0.f,0.f}, v2f{0.f,0.f}, v2f{0.f,0.f}, v2f{0.f,0.f}};

        const float* wg = &ws[cc * WS_C + g * WS_G];
        #pragma unroll
        for (int k = 0; k < KK; ++k) {
            v2f a0 = {0.f,0.f}, a1 = {0.f,0.f}, a2 = {0.f,0.f}, a3 = {0.f,0.f};
            #pragma unroll
            for (int l = 0; l < 4; ++l) {
                const float xsv = xv4[k][l];
                const v2f xs2 = {xsv, xsv};
                const v4f w01 = *reinterpret_cast<const v4f*>(wg + k * 32 + l * 8);
                const v4f w23 = *reinterpret_cast<const v4f*>(wg + k * 32 + l * 8 + 4);
                a0 = fma2(xs2, __builtin_shufflevector(w01, w01, 0, 1), a0);
                a1 = fma2(xs2, __builtin_shufflevector(w01, w01, 2, 3), a1);
                a2 = fma2(xs2, __builtin_shufflevector(w23, w23, 0, 1), a2);
                a3 = fma2(xs2, __builtin_shufflevector(w23, w23, 2, 3), a3);
            }
            pr2[k][0] = a0; pr2[k][1] = a1; pr2[k][2] = a2; pr2[k][3] = a3;
            ks2[0] += a0; ks2[1] += a1; ks2[2] += a2; ks2[3] += a3;
        }

        // ---- dynamic routing, ITERS = 3 (normalized probs — bounded) ----
        float logits[KK];
        #pragma unroll
        for (int k = 0; k < KK; ++k) logits[k] = 0.0f;

        v2f vv[4];
        #pragma unroll
        for (int it = 0; it < 3; ++it) {
            v2f s2[4];
            float pre;   // scale applied to the reduced raw sum before squash
            if (it == 0) {
                #pragma unroll
                for (int j = 0; j < 4; ++j) s2[j] = ks2[j];
                pre = 1.0f / 9.0f;
            } else {
                float e[KK];
                float sum = 0.0f;
                #pragma unroll
                for (int k = 0; k < KK; ++k) { e[k] = __expf(logits[k]); sum += e[k]; }
                const float inv = __builtin_amdgcn_rcpf(sum);  // sum bounded: safe
                #pragma unroll
                for (int j = 0; j < 4; ++j) s2[j] = v2f{0.f, 0.f};
                #pragma unroll
                for (int k = 0; k < KK; ++k) {
                    const v2f ek = {e[k], e[k]};
                    #pragma unroll
                    for (int j = 0; j < 4; ++j) s2[j] = fma2(ek, pr2[k][j], s2[j]);
                }
                const v2f inv2 = {inv, inv};
                #pragma unroll
                for (int j = 0; j < 4; ++j) s2[j] *= inv2;
                pre = 1.0f;
            }

            // g-group all-reduce via DPP (VALU-only, no LDS pipe)
            #pragma unroll
            for (int j = 0; j < 4; ++j) { DPP_XADD(s2[j].x, 0xB1); DPP_XADD(s2[j].y, 0xB1); }
            #pragma unroll
            for (int j = 0; j < 4; ++j) { DPP_XADD(s2[j].x, 0x4E); DPP_XADD(s2[j].y, 0x4E); }
            #pragma unroll
            for (int j = 0; j < 4; ++j) { DPP_XADD(s2[j].x, 0x141); DPP_XADD(s2[j].y, 0x141); }

            // squash on s_true = pre*s2: n2 = pre^2*|s2|^2, v = (pre*f)*s2
            v2f tq = s2[0] * s2[0];
            tq = fma2(s2[1], s2[1], tq);
            tq = fma2(s2[2], s2[2], tq);
            tq = fma2(s2[3], s2[3], tq);
            const float n2 = (tq.x + tq.y) * (pre * pre);
            const float f = n2 * __builtin_amdgcn_rsqf(fmaxf(n2, 1e-30f))
                               * __builtin_amdgcn_rcpf(1.0f + n2);
            const float q = f * pre;
            const v2f q2 = {q, q};
            #pragma unroll
            for (int j = 0; j < 4; ++j) vv[j] = q2 * s2[j];

            if (it != 2) {
                #pragma unroll
                for (int k = 0; k < KK; ++k) {
                    v2f d2 = pr2[k][0] * vv[0];
                    d2 = fma2(pr2[k][1], vv[1], d2);
                    d2 = fma2(pr2[k][2], vv[2], d2);
                    d2 = fma2(pr2[k][3], vv[3], d2);
                    logits[k] += d2.x + d2.y;
                }
            }
        }

        // lane (w, g) writes output component m = g (static select chain)
        const float vs[8] = { vv[0].x, vv[0].y, vv[1].x, vv[1].y,
                              vv[2].x, vv[2].y, vv[3].x, vv[3].y };
        float outv = vs[0];
        #pragma unroll
        for (int m = 1; m < LOUT; ++m) if (g == m) outv = vs[m];
        out[(n * GOUT * LOUT + (c0 + cc) * LOUT + g) * HW + h * WW + w] = outv;
    }
}

extern "C" void kernel_launch(void* const* d_in, const int* in_sizes, int n_in,
                              void* d_out, int out_size, void* d_ws, size_t ws_size,
                              hipStream_t stream) {
    const float* x  = (const float*)d_in[0];
    const float* wt = (const float*)d_in[1];
    float* out = (float*)d_out;
    float* xt = (float*)d_ws;   // 4*58*58*32 floats = 1.72 MB scratch

    transpose_x_kernel<<<dim3(NB * HP), dim3(256), 0, stream>>>(x, xt);
    dim3 grid(NB * HH, GOUT / CPB);   // 224 x 4, 448 threads (one row x two c's)
    caps_routing_kernel<<<grid, dim3(THREADS), 0, stream>>>(xt, wt, out);
}

// Round 31
// 31.062 us; speedup vs baseline: 1.0712x; 1.0712x over previous
//
#include <hip/hip_runtime.h>

#define NB   4
#define CIN  32
#define HH   56
#define WW   56
#define GOUT 8
#define LOUT 8
#define KK   9
#define HW   (HH * WW)        // 3136
#define WSLICE 2304           // GOUT-slice floats per c (8*9*4*8)
#define WS_G 292              // padded per-g LDS stride -> conflict-free float4 reads
#define HP   58               // padded spatial dims
#define WP   58
#define THREADS 448           // one image row: 56 px * 8 g

typedef float v2f __attribute__((ext_vector_type(2)));
typedef float v4f __attribute__((ext_vector_type(4)));

static __device__ __forceinline__ v2f fma2(v2f a, v2f b, v2f c) {
    return __builtin_elementwise_fma(a, b, c);
}

// DPP xor-add over the 8-lane g-group: quad_perm(1,0,3,2)=0xB1 (lane^1),
// quad_perm(2,3,0,1)=0x4E (lane^2), row_half_mirror=0x141 (lane^7 within 8;
// valid for step 3 because quad-sums are already quad-uniform).
#define DPP_XADD(x, CTRL) \
    (x) += __int_as_float(__builtin_amdgcn_update_dpp( \
        0, __float_as_int(x), (CTRL), 0xF, 0xF, true))

// ---- pre-pass: x[n][ch][h][w] -> xt[n][hp][wp][ch] with zero border ----
__global__ __launch_bounds__(256) void transpose_x_kernel(
    const float* __restrict__ x, float* __restrict__ xt)
{
    __shared__ float tile[CIN * 57];     // 57 stride: conflict-free transposed read
    const int b = blockIdx.x;            // n*HP + hp
    const int n = b / HP;
    const int hp = b - n * HP;
    const int h = hp - 1;
    const int tid = threadIdx.x;
    const bool rowok = (unsigned)h < (unsigned)HH;

    if (rowok) {
        for (int i = tid; i < CIN * WW; i += 256) {
            const int ch = i / WW;
            const int w  = i - ch * WW;  // lanes: w consecutive -> coalesced read
            tile[ch * 57 + w] = x[((n * CIN + ch) * HH + h) * WW + w];
        }
    }
    __syncthreads();
    float* dst = xt + ((size_t)(n * HP + hp) * WP) * CIN;
    for (int i = tid; i < WP * CIN; i += 256) {
        const int wp = i >> 5;
        const int ch = i & 31;           // lanes: ch consecutive -> coalesced write
        const bool ok = rowok && (wp >= 1) && (wp <= WW);
        dst[i] = ok ? tile[ch * 57 + (wp - 1)] : 0.0f;
    }
}

__global__ __launch_bounds__(THREADS, 2) void caps_routing_kernel(
    const float* __restrict__ xt, const float* __restrict__ wt,
    float* __restrict__ out)
{
    __shared__ __align__(16) float ws[8 * WS_G];   // 9344 B

    const int tid = threadIdx.x;
    const int c = blockIdx.y;
    const int rr = blockIdx.x;        // n*56 + h  (block-uniform -> SALU math)
    const int n = rr / HH;
    const int h = rr - n * HH;

    const int g = tid & 7;
    const int w = tid >> 3;           // 0..55

    // ---- x-gather: 9 unconditional float4 loads (padded layout) ----
    v4f xv4[KK];
    const float* base = xt + ((size_t)((n * HP + h) * WP + w)) * CIN + g * 4;
    #pragma unroll
    for (int ki = 0; ki < 3; ++ki)
        #pragma unroll
        for (int kj = 0; kj < 3; ++kj)
            xv4[ki * 3 + kj] =
                *reinterpret_cast<const v4f*>(base + (ki * WP + kj) * CIN);

    // ---- stage this c's weight slice: [g][k][l][m], per-g padded to 292 ----
    if (tid < 256) {
        const int gg = tid >> 5;
        const int r0 = tid & 31;
        const float* src = wt + c * WSLICE + gg * 288;
        float* dst = ws + gg * WS_G;
        #pragma unroll
        for (int j = 0; j < 9; ++j)
            dst[r0 + j * 32] = src[r0 + j * 32];
    }
    __syncthreads();

    // ---- priors (packed pairs): pr2[k][j] = m-pair j of prior vector k ----
    v2f pr2[KK][4];
    v2f ks2[4] = {v2f{0.f,0.f}, v2f{0.f,0.f}, v2f{0.f,0.f}, v2f{0.f,0.f}};

    const float* wg = &ws[g * WS_G];
    #pragma unroll
    for (int k = 0; k < KK; ++k) {
        v2f a0 = {0.f,0.f}, a1 = {0.f,0.f}, a2 = {0.f,0.f}, a3 = {0.f,0.f};
        #pragma unroll
        for (int l = 0; l < 4; ++l) {
            const float xsv = xv4[k][l];
            const v2f xs2 = {xsv, xsv};
            const v4f w01 = *reinterpret_cast<const v4f*>(wg + k * 32 + l * 8);
            const v4f w23 = *reinterpret_cast<const v4f*>(wg + k * 32 + l * 8 + 4);
            a0 = fma2(xs2, __builtin_shufflevector(w01, w01, 0, 1), a0);
            a1 = fma2(xs2, __builtin_shufflevector(w01, w01, 2, 3), a1);
            a2 = fma2(xs2, __builtin_shufflevector(w23, w23, 0, 1), a2);
            a3 = fma2(xs2, __builtin_shufflevector(w23, w23, 2, 3), a3);
        }
        pr2[k][0] = a0; pr2[k][1] = a1; pr2[k][2] = a2; pr2[k][3] = a3;
        ks2[0] += a0; ks2[1] += a1; ks2[2] += a2; ks2[3] += a3;
    }

    // ---- dynamic routing, ITERS = 3 (normalized probs — bounded) ----
    float logits[KK];
    #pragma unroll
    for (int k = 0; k < KK; ++k) logits[k] = 0.0f;

    v2f vv[4];
    #pragma unroll
    for (int it = 0; it < 3; ++it) {
        v2f s2[4];
        float pre;   // scale applied to the reduced raw sum before squash
        if (it == 0) {
            #pragma unroll
            for (int j = 0; j < 4; ++j) s2[j] = ks2[j];
            pre = 1.0f / 9.0f;
        } else {
            float e[KK];
            float sum = 0.0f;
            #pragma unroll
            for (int k = 0; k < KK; ++k) { e[k] = __expf(logits[k]); sum += e[k]; }
            const float inv = __builtin_amdgcn_rcpf(sum);  // sum in [~1e-12, 3e4]: safe
            #pragma unroll
            for (int j = 0; j < 4; ++j) s2[j] = v2f{0.f, 0.f};
            #pragma unroll
            for (int k = 0; k < KK; ++k) {
                const v2f ek = {e[k], e[k]};
                #pragma unroll
                for (int j = 0; j < 4; ++j) s2[j] = fma2(ek, pr2[k][j], s2[j]);
            }
            const v2f inv2 = {inv, inv};
            #pragma unroll
            for (int j = 0; j < 4; ++j) s2[j] *= inv2;
            pre = 1.0f;
        }

        // g-group all-reduce via DPP (VALU-only, no LDS pipe)
        #pragma unroll
        for (int j = 0; j < 4; ++j) { DPP_XADD(s2[j].x, 0xB1); DPP_XADD(s2[j].y, 0xB1); }
        #pragma unroll
        for (int j = 0; j < 4; ++j) { DPP_XADD(s2[j].x, 0x4E); DPP_XADD(s2[j].y, 0x4E); }
        #pragma unroll
        for (int j = 0; j < 4; ++j) { DPP_XADD(s2[j].x, 0x141); DPP_XADD(s2[j].y, 0x141); }

        // squash on s_true = pre*s2: n2 = pre^2*|s2|^2, v = (pre*f)*s2
        v2f tq = s2[0] * s2[0];
        tq = fma2(s2[1], s2[1], tq);
        tq = fma2(s2[2], s2[2], tq);
        tq = fma2(s2[3], s2[3], tq);
        const float n2 = (tq.x + tq.y) * (pre * pre);
        const float f = n2 * __builtin_amdgcn_rsqf(fmaxf(n2, 1e-30f))
                           * __builtin_amdgcn_rcpf(1.0f + n2);
        const float q = f * pre;
        const v2f q2 = {q, q};
        #pragma unroll
        for (int j = 0; j < 4; ++j) vv[j] = q2 * s2[j];

        if (it != 2) {
            #pragma unroll
            for (int k = 0; k < KK; ++k) {
                v2f d2 = pr2[k][0] * vv[0];
                d2 = fma2(pr2[k][1], vv[1], d2);
                d2 = fma2(pr2[k][2], vv[2], d2);
                d2 = fma2(pr2[k][3], vv[3], d2);
                logits[k] += d2.x + d2.y;
            }
        }
    }

    // lane (w, g) writes output component m = g (static select chain)
    const float vs[8] = { vv[0].x, vv[0].y, vv[1].x, vv[1].y,
                          vv[2].x, vv[2].y, vv[3].x, vv[3].y };
    float outv = vs[0];
    #pragma unroll
    for (int m = 1; m < LOUT; ++m) if (g == m) outv = vs[m];
    out[(n * GOUT * LOUT + c * LOUT + g) * HW + h * WW + w] = outv;
}

extern "C" void kernel_launch(void* const* d_in, const int* in_sizes, int n_in,
                              void* d_out, int out_size, void* d_ws, size_t ws_size,
                              hipStream_t stream) {
    const float* x  = (const float*)d_in[0];
    const float* wt = (const float*)d_in[1];
    float* out = (float*)d_out;
    float* xt = (float*)d_ws;   // 4*58*58*32 floats = 1.72 MB scratch

    transpose_x_kernel<<<dim3(NB * HP), dim3(256), 0, stream>>>(x, xt);
    dim3 grid(NB * HH, GOUT);   // 224 x 8, 448 threads (one row x one c)
    caps_routing_kernel<<<grid, dim3(THREADS), 0, stream>>>(xt, wt, out);
}